// Round 9
// baseline (241.103 us; speedup 1.0000x reference)
//
#include <hip/hip_runtime.h>
#include <cstddef>

#define NB 256     // graphs
#define M 512      // nodes per graph
#define KNN 6      // neighbors
#define C 32       // channels
#define NTOT (NB*M)

// ---------------------------------------------------------------------------
// KNN v3 (round-7 verbatim, absmax 0.0): 2 blocks/graph x 512 threads; each
// thread scans 128 cols for TWO rows; ushort cand ids; ascending-part merge.
// ---------------------------------------------------------------------------
__global__ __launch_bounds__(512) void knn_kernel(const float* __restrict__ pos,
                                                  int* __restrict__ idx)
{
    __shared__ float4 sp[M];                        // 8 KB
    __shared__ float  cd[1024][7];                  // 28 KB
    __shared__ unsigned short ci[1024][7];          // 14 KB

    const int b    = blockIdx.x;      // 0..511
    const int g    = b >> 1;
    const int half = b & 1;
    const int tid  = threadIdx.x;

    const float* p = pos + (size_t)g * M * 3;
    for (int i = tid; i < M; i += 512) {
        float x = p[3 * i], y = p[3 * i + 1], z = p[3 * i + 2];
        sp[i] = make_float4(x, y, z, fmaf(x, x, fmaf(y, y, z * z)));
    }
    __syncthreads();

    const int part = tid >> 7;
    const int rloc = tid & 127;
    const int ra   = half * 256 + rloc;
    const int rb   = ra + 128;

    const float4 pa = sp[ra];
    const float4 pb = sp[rb];

    float da[KNN], db[KNN];
    int   ia[KNN], ib[KNN];
#pragma unroll
    for (int k = 0; k < KNN; k++) {
        da[k] = INFINITY; db[k] = INFINITY; ia[k] = -1; ib[k] = -1;
    }

    const int n0 = part * 128;
#pragma unroll 4
    for (int jj = 0; jj < 128; jj++) {
        const int n = n0 + jj;
        const float4 pn = sp[n];

        float dotA = fmaf(pa.x, pn.x, fmaf(pa.y, pn.y, pa.z * pn.z));
        float dA   = fmaf(-2.f, dotA, pa.w + pn.w);
        float dotB = fmaf(pb.x, pn.x, fmaf(pb.y, pn.y, pb.z * pn.z));
        float dB   = fmaf(-2.f, dotB, pb.w + pn.w);

#pragma unroll
        for (int k = KNN - 1; k > 0; k--) {
            bool ck  = dA < da[k];
            bool ck1 = dA < da[k - 1];
            da[k] = ck1 ? da[k - 1] : (ck ? dA : da[k]);
            ia[k] = ck1 ? ia[k - 1] : (ck ? n  : ia[k]);
        }
        bool cA = dA < da[0];
        da[0] = cA ? dA : da[0];
        ia[0] = cA ? n  : ia[0];

#pragma unroll
        for (int k = KNN - 1; k > 0; k--) {
            bool ck  = dB < db[k];
            bool ck1 = dB < db[k - 1];
            db[k] = ck1 ? db[k - 1] : (ck ? dB : db[k]);
            ib[k] = ck1 ? ib[k - 1] : (ck ? n  : ib[k]);
        }
        bool cB = dB < db[0];
        db[0] = cB ? dB : db[0];
        ib[0] = cB ? n  : ib[0];
    }

    {
        const int La = part * 256 + rloc;
        const int Lb = La + 128;
#pragma unroll
        for (int k = 0; k < KNN; k++) {
            cd[La][k] = da[k]; ci[La][k] = (unsigned short)ia[k];
            cd[Lb][k] = db[k]; ci[Lb][k] = (unsigned short)ib[k];
        }
    }
    __syncthreads();

    if (tid < 256) {
        const int m = tid;
        float md[KNN]; int mi[KNN];
#pragma unroll
        for (int k = 0; k < KNN; k++) { md[k] = cd[m][k]; mi[k] = ci[m][k]; }
#pragma unroll
        for (int pp = 1; pp < 4; pp++) {
            const int L = pp * 256 + m;
#pragma unroll
            for (int k = 0; k < KNN; k++) {
                float dist = cd[L][k];
                int   n    = ci[L][k];
#pragma unroll
                for (int q = KNN - 1; q > 0; q--) {
                    bool cq  = dist < md[q];
                    bool cq1 = dist < md[q - 1];
                    md[q] = cq1 ? md[q - 1] : (cq ? dist : md[q]);
                    mi[q] = cq1 ? mi[q - 1] : (cq ? n    : mi[q]);
                }
                bool c0 = dist < md[0];
                md[0] = c0 ? dist : md[0];
                mi[0] = c0 ? n    : mi[0];
            }
        }
        const int node = g * M + half * 256 + m;
#pragma unroll
        for (int k = 0; k < KNN; k++)
            idx[k * NTOT + node] = g * M + mi[k];
    }
}

// ---------------------------------------------------------------------------
// Fused layers 1-3 + pool + head. 2 blocks/graph (redundant compute, half==0
// writes out) for 2 blocks/CU occupancy. ROUND-9 FIX: __launch_bounds__(512,2)
// -> VGPR cap >= 128 (round-8's (512,4) capped at 64 -> 40 MB spill traffic,
// VGPR_Count=64, WRITE_SIZE=22.5 MB; kernel naturally wants ~72-100).
// ---------------------------------------------------------------------------
template <int IN>
__device__ __forceinline__ void gcn_layer_fused(float (&h)[C],
    const float* __restrict__ W1, const float* __restrict__ b1,
    const float* __restrict__ W2, const float* __restrict__ b2,
    float* Ts, int t, const int (&j)[KNN])
{
    float m1[C];
#pragma unroll
    for (int o = 0; o < C; o++) {
        float a = b1[o];
#pragma unroll
        for (int i = 0; i < IN; i++) a = fmaf(W1[o * IN + i], h[i], a);
        m1[o] = fmaxf(a, 0.f);
    }

    const int tp = t & 7;
#pragma unroll
    for (int q = 0; q < 8; q++) {
        float4 v;
        float* vp = &v.x;
#pragma unroll
        for (int u = 0; u < 4; u++) {
            const int o = 4 * q + u;
            float a = b2[o];
#pragma unroll
            for (int i = 0; i < C; i++) a = fmaf(W2[o * C + i], m1[i], a);
            vp[u] = a;
        }
        *(float4*)&Ts[t * C + ((q ^ tp) << 2)] = v;
    }
    __syncthreads();

#pragma unroll
    for (int c = 0; c < C; c++) h[c] = -INFINITY;
#pragma unroll
    for (int k = 0; k < KNN; k++) {
        const int jl = j[k], jp = jl & 7;
#pragma unroll
        for (int q = 0; q < 8; q++) {
            const float4 v = *(const float4*)&Ts[jl * C + ((q ^ jp) << 2)];
            h[4*q+0] = fmaxf(h[4*q+0], v.x);
            h[4*q+1] = fmaxf(h[4*q+1], v.y);
            h[4*q+2] = fmaxf(h[4*q+2], v.z);
            h[4*q+3] = fmaxf(h[4*q+3], v.w);
        }
    }
#pragma unroll
    for (int c = 0; c < C; c++) h[c] = fmaxf(h[c], 0.f);
    __syncthreads();
}

__global__ __launch_bounds__(512, 2) void fused_kernel(
    const float* __restrict__ x, const float* __restrict__ pos,
    const int* __restrict__ idx,
    const float* __restrict__ W1a, const float* __restrict__ b1a,
    const float* __restrict__ W2a, const float* __restrict__ b2a,
    const float* __restrict__ W1b, const float* __restrict__ b1b,
    const float* __restrict__ W2b, const float* __restrict__ b2b,
    const float* __restrict__ W1c, const float* __restrict__ b1c,
    const float* __restrict__ W2c, const float* __restrict__ b2c,
    const float* __restrict__ Wr,  const float* __restrict__ br,
    float* __restrict__ out)
{
    __shared__ __align__(16) float Ts[M * C];   // 64 KB
    const int g = blockIdx.x >> 1, half = blockIdx.x & 1;
    const int t = threadIdx.x;
    const int n = g * M + t;

    int j[KNN];
#pragma unroll
    for (int k = 0; k < KNN; k++) j[k] = idx[k * NTOT + n] & (M - 1);

    float h[C];
    h[0] = x[n];
    h[1] = pos[3 * n];
    h[2] = pos[3 * n + 1];
    h[3] = pos[3 * n + 2];

    gcn_layer_fused<4>(h, W1a, b1a, W2a, b2a, Ts, t, j);
    gcn_layer_fused<C>(h, W1b, b1b, W2b, b2b, Ts, t, j);
    gcn_layer_fused<C>(h, W1c, b1c, W2c, b2c, Ts, t, j);

    const int tp = t & 7;
#pragma unroll
    for (int q = 0; q < 8; q++) {
        float4 v = make_float4(h[4*q], h[4*q+1], h[4*q+2], h[4*q+3]);
        *(float4*)&Ts[t * C + ((q ^ tp) << 2)] = v;
    }
    __syncthreads();

    for (int s = 256; s >= 32; s >>= 1) {
        if (t < s) {
#pragma unroll
            for (int q = 0; q < 8; q++) {
                const int ph = (q ^ tp) << 2;
                float4 a = *(const float4*)&Ts[t * C + ph];
                float4 b = *(const float4*)&Ts[(t + s) * C + ph];
                a.x = fmaxf(a.x, b.x); a.y = fmaxf(a.y, b.y);
                a.z = fmaxf(a.z, b.z); a.w = fmaxf(a.w, b.w);
                *(float4*)&Ts[t * C + ph] = a;
            }
        }
        __syncthreads();
    }

    if (t < C) {
        float m = -INFINITY;
#pragma unroll
        for (int r = 0; r < 32; r++)
            m = fmaxf(m, Ts[r * C + ((((t >> 2) ^ (r & 7)) << 2) | (t & 3))]);
        Ts[t] = m;
    }
    __syncthreads();

    if (half == 0 && t < 6) {
        float a = br[t];
#pragma unroll
        for (int i = 0; i < C; i++) a = fmaf(Wr[t * C + i], Ts[i], a);
        out[g * 6 + t] = a;
    }
}

extern "C" void kernel_launch(void* const* d_in, const int* in_sizes, int n_in,
                              void* d_out, int out_size, void* d_ws, size_t ws_size,
                              hipStream_t stream) {
    const float* x   = (const float*)d_in[0];
    const float* pos = (const float*)d_in[1];
    // d_in[2] = batch (int64) unused: nodes are contiguous M-per-graph
    const float* W1a = (const float*)d_in[3];
    const float* b1a = (const float*)d_in[4];
    const float* W2a = (const float*)d_in[5];
    const float* b2a = (const float*)d_in[6];
    const float* W1b = (const float*)d_in[7];
    const float* b1b = (const float*)d_in[8];
    const float* W2b = (const float*)d_in[9];
    const float* b2b = (const float*)d_in[10];
    const float* W1c = (const float*)d_in[11];
    const float* b1c = (const float*)d_in[12];
    const float* W2c = (const float*)d_in[13];
    const float* b2c = (const float*)d_in[14];
    const float* Wr  = (const float*)d_in[15];
    const float* br  = (const float*)d_in[16];

    int*   idx = (int*)d_ws;   // 3 MB [KNN][NTOT]
    float* out = (float*)d_out;

    knn_kernel<<<NB * 2, 512, 0, stream>>>(pos, idx);

    fused_kernel<<<NB * 2, 512, 0, stream>>>(x, pos, idx,
                                             W1a, b1a, W2a, b2a,
                                             W1b, b1b, W2b, b2b,
                                             W1c, b1c, W2c, b2c,
                                             Wr, br, out);
}

// Round 10
// 202.100 us; speedup vs baseline: 1.1930x; 1.1930x over previous
//
#include <hip/hip_runtime.h>
#include <cstddef>

#define NB 256     // graphs
#define M 512      // nodes per graph
#define KNN 6      // neighbors
#define C 32       // channels

// ---------------------------------------------------------------------------
// ONE kernel: block = graph (1024 threads = 512 nodes x 2 channel-halves),
// phases: in-block KNN -> L1 -> L2 -> L3 -> pool -> head.
//   thread t: node n = t&511, half hv = t>>9 (wave-uniform), channels
//   c0..c0+15 with c0 = hv*16.
// Channel-split halves per-thread live state (~85 VGPR < 128 granule cap) so
// a single 1024-thread block gives 16 waves/CU (rounds 7-9: 512-thr blocks
// could not have both >=16 waves/CU and >=72 VGPR).
// KNN: thread scans 256 cols for its row (work-conserving vs validated v3),
// bit-identical distance chain, strict-< insert, ascending 2-list merge
// (tie-stable, lowest index wins) -> j[6] lives in REGISTERS; no idx memory.
// T staged in 64 KB LDS, float4-chunk XOR swizzle (row n, chunk q at
// n*32 + ((q^(n&7))<<2)); KNN scratch overlays the same 64 KB before use.
// ---------------------------------------------------------------------------
__global__ __launch_bounds__(1024, 1) void megafused_kernel(
    const float* __restrict__ x, const float* __restrict__ pos,
    const float* __restrict__ W1a, const float* __restrict__ b1a,
    const float* __restrict__ W2a, const float* __restrict__ b2a,
    const float* __restrict__ W1b, const float* __restrict__ b1b,
    const float* __restrict__ W2b, const float* __restrict__ b2b,
    const float* __restrict__ W1c, const float* __restrict__ b1c,
    const float* __restrict__ W2c, const float* __restrict__ b2c,
    const float* __restrict__ Wr,  const float* __restrict__ br,
    float* __restrict__ out)
{
    __shared__ __align__(16) float Ts[M * C];   // 64 KB, multi-purpose
    const int g  = blockIdx.x;
    const int t  = threadIdx.x;
    const int n  = t & (M - 1);                 // node 0..511
    const int hv = t >> 9;                      // 0/1, wave-uniform
    const int c0 = __builtin_amdgcn_readfirstlane(hv << 4); // force SGPR weights

    // ---- overlay for KNN phase (all within the 64 KB of Ts) ----
    float4* sp          = (float4*)Ts;                          // [0, 8K) B
    float*  cd          = Ts + 2048;                            // [8K, 36K) B, stride 7
    unsigned short* ci  = (unsigned short*)(Ts + 2048 + 7168);  // [36K, 50K) B

    // === phase 0: positions + squared norms into LDS ===
    const float* p = pos + (size_t)g * M * 3;
    if (t < M) {
        float xx = p[3*t], yy = p[3*t+1], zz = p[3*t+2];
        sp[t] = make_float4(xx, yy, zz, fmaf(xx, xx, fmaf(yy, yy, zz * zz)));
    }
    __syncthreads();

    const float4 pm = sp[n];   // this node's pos (reused for layer 1)

    // === phase 1: KNN scan — row n, cols [hv*256, hv*256+256) ===
    float d[KNN]; int id[KNN];
#pragma unroll
    for (int k = 0; k < KNN; k++) { d[k] = INFINITY; id[k] = -1; }

    const int col0 = hv << 8;
#pragma unroll 4
    for (int jj = 0; jj < 256; jj++) {
        const int col = col0 + jj;
        const float4 pn = sp[col];                       // wave-uniform: broadcast
        float dot  = fmaf(pm.x, pn.x, fmaf(pm.y, pn.y, pm.z * pn.z));
        float dist = fmaf(-2.f, dot, pm.w + pn.w);       // validated rounding chain
#pragma unroll
        for (int k = KNN - 1; k > 0; k--) {              // strict-< sorted insert
            bool ck  = dist < d[k];
            bool ck1 = dist < d[k - 1];
            d[k]  = ck1 ? d[k - 1]  : (ck ? dist : d[k]);
            id[k] = ck1 ? id[k - 1] : (ck ? col  : id[k]);
        }
        bool c0b = dist < d[0];
        d[0]  = c0b ? dist : d[0];
        id[0] = c0b ? col  : id[0];
    }
#pragma unroll
    for (int k = 0; k < KNN; k++) {
        cd[t * 7 + k] = d[k];
        ci[t * 7 + k] = (unsigned short)id[k];
    }
    __syncthreads();

    // === phase 2: merge the two 6-lists of node n (ascending col halves ->
    // strict-< insert is tie-stable toward lower index). Both half-threads
    // compute the same j[] redundantly; it stays in registers. ===
    int j[KNN];
    {
        float md[KNN]; int mi[KNN];
#pragma unroll
        for (int k = 0; k < KNN; k++) { md[k] = cd[n*7 + k]; mi[k] = ci[n*7 + k]; }
        const int L1 = (n + M) * 7;
#pragma unroll
        for (int k = 0; k < KNN; k++) {
            float dist = cd[L1 + k];
            int   nn   = ci[L1 + k];
#pragma unroll
            for (int q = KNN - 1; q > 0; q--) {
                bool cq  = dist < md[q];
                bool cq1 = dist < md[q - 1];
                md[q] = cq1 ? md[q - 1] : (cq ? dist : md[q]);
                mi[q] = cq1 ? mi[q - 1] : (cq ? nn   : mi[q]);
            }
            bool cb = dist < md[0];
            md[0] = cb ? dist : md[0];
            mi[0] = cb ? nn   : mi[0];
        }
#pragma unroll
        for (int k = 0; k < KNN; k++) j[k] = mi[k];
    }
    __syncthreads();   // KNN scratch dead; Ts becomes the T-staging buffer

    const int np = n & 7;

    // === layer 1: T1 = MLP_a([x,pos]) — no gather ===
    {
        const float h0 = x[(size_t)g * M + n];
        const float h1 = pm.x, h2 = pm.y, h3 = pm.z;
        float m1[C];
#pragma unroll
        for (int o = 0; o < C; o++) {
            float a = b1a[o];
            a = fmaf(W1a[o*4+0], h0, a);
            a = fmaf(W1a[o*4+1], h1, a);
            a = fmaf(W1a[o*4+2], h2, a);
            a = fmaf(W1a[o*4+3], h3, a);
            m1[o] = fmaxf(a, 0.f);
        }
#pragma unroll
        for (int q2 = 0; q2 < 4; q2++) {
            float4 v; float* vp = &v.x;
#pragma unroll
            for (int u = 0; u < 4; u++) {
                const int o = c0 + q2*4 + u;
                float a = b2a[o];
#pragma unroll
                for (int i = 0; i < C; i++) a = fmaf(W2a[o*C + i], m1[i], a);
                vp[u] = a;
            }
            const int q = 4*hv + q2;
            *(float4*)&Ts[n*C + ((q ^ np) << 2)] = v;
        }
    }
    __syncthreads();

    // === layers 2,3 ===
#pragma unroll 1
    for (int layer = 0; layer < 2; layer++) {
        const float* W1 = layer ? W1c : W1b;
        const float* b1 = layer ? b1c : b1b;
        const float* W2 = layer ? W2c : W2b;
        const float* b2 = layer ? b2c : b2b;

        // A: aggregate neighbors' half-rows -> hm[16], relu
        float hm[16];
#pragma unroll
        for (int u = 0; u < 16; u++) hm[u] = -INFINITY;
#pragma unroll
        for (int k = 0; k < KNN; k++) {
            const int jl = j[k], jp = jl & 7;
#pragma unroll
            for (int q2 = 0; q2 < 4; q2++) {
                const int q = 4*hv + q2;
                const float4 v = *(const float4*)&Ts[jl*C + ((q ^ jp) << 2)];
                hm[4*q2+0] = fmaxf(hm[4*q2+0], v.x);
                hm[4*q2+1] = fmaxf(hm[4*q2+1], v.y);
                hm[4*q2+2] = fmaxf(hm[4*q2+2], v.z);
                hm[4*q2+3] = fmaxf(hm[4*q2+3], v.w);
            }
        }
#pragma unroll
        for (int u = 0; u < 16; u++) hm[u] = fmaxf(hm[u], 0.f);
        __syncthreads();              // all T reads done
        // B: write h half-row (overwrites T)
#pragma unroll
        for (int q2 = 0; q2 < 4; q2++) {
            const int q = 4*hv + q2;
            *(float4*)&Ts[n*C + ((q ^ np) << 2)] =
                make_float4(hm[4*q2], hm[4*q2+1], hm[4*q2+2], hm[4*q2+3]);
        }
        __syncthreads();              // h visible
        // C: read full h row of own node
        float hf[C];
#pragma unroll
        for (int q = 0; q < 8; q++) {
            const float4 v = *(const float4*)&Ts[n*C + ((q ^ np) << 2)];
            hf[4*q+0] = v.x; hf[4*q+1] = v.y; hf[4*q+2] = v.z; hf[4*q+3] = v.w;
        }
        __syncthreads();              // h reads done (T write below may alias)
        // full m1 (both halves duplicate: saves an LDS exchange + 2 barriers)
        float m1[C];
#pragma unroll
        for (int o = 0; o < C; o++) {
            float a = b1[o];
#pragma unroll
            for (int i = 0; i < C; i++) a = fmaf(W1[o*C + i], hf[i], a);
            m1[o] = fmaxf(a, 0.f);
        }
        // T half-row
#pragma unroll
        for (int q2 = 0; q2 < 4; q2++) {
            float4 v; float* vp = &v.x;
#pragma unroll
            for (int u = 0; u < 4; u++) {
                const int o = c0 + q2*4 + u;
                float a = b2[o];
#pragma unroll
                for (int i = 0; i < C; i++) a = fmaf(W2[o*C + i], m1[i], a);
                vp[u] = a;
            }
            const int q = 4*hv + q2;
            *(float4*)&Ts[n*C + ((q ^ np) << 2)] = v;
        }
        __syncthreads();              // T visible
    }

    // === final aggregation (h3) for pooling ===
    {
        float hm[16];
#pragma unroll
        for (int u = 0; u < 16; u++) hm[u] = -INFINITY;
#pragma unroll
        for (int k = 0; k < KNN; k++) {
            const int jl = j[k], jp = jl & 7;
#pragma unroll
            for (int q2 = 0; q2 < 4; q2++) {
                const int q = 4*hv + q2;
                const float4 v = *(const float4*)&Ts[jl*C + ((q ^ jp) << 2)];
                hm[4*q2+0] = fmaxf(hm[4*q2+0], v.x);
                hm[4*q2+1] = fmaxf(hm[4*q2+1], v.y);
                hm[4*q2+2] = fmaxf(hm[4*q2+2], v.z);
                hm[4*q2+3] = fmaxf(hm[4*q2+3], v.w);
            }
        }
        __syncthreads();              // all T3 reads done
#pragma unroll
        for (int q2 = 0; q2 < 4; q2++) {
            const int q = 4*hv + q2;
            *(float4*)&Ts[n*C + ((q ^ np) << 2)] =
                make_float4(fmaxf(hm[4*q2+0], 0.f), fmaxf(hm[4*q2+1], 0.f),
                            fmaxf(hm[4*q2+2], 0.f), fmaxf(hm[4*q2+3], 0.f));
        }
        __syncthreads();
    }

    // === global max pool: tree reduce rows 512 -> 32 (round-6 validated) ===
    const int tp = t & 7;
    for (int s = 256; s >= 32; s >>= 1) {
        if (t < s) {
#pragma unroll
            for (int q = 0; q < 8; q++) {
                const int ph = (q ^ tp) << 2;
                float4 a = *(const float4*)&Ts[t*C + ph];
                float4 b = *(const float4*)&Ts[(t + s)*C + ph];
                a.x = fmaxf(a.x, b.x); a.y = fmaxf(a.y, b.y);
                a.z = fmaxf(a.z, b.z); a.w = fmaxf(a.w, b.w);
                *(float4*)&Ts[t*C + ph] = a;
            }
        }
        __syncthreads();
    }

    if (t < C) {   // wave 0: reduce final 32 rows (reads precede write in-wave)
        float m = -INFINITY;
#pragma unroll
        for (int r = 0; r < 32; r++)
            m = fmaxf(m, Ts[r*C + ((((t >> 2) ^ (r & 7)) << 2) | (t & 3))]);
        Ts[t] = m;
    }
    __syncthreads();

    if (t < 6) {
        float a = br[t];
#pragma unroll
        for (int i = 0; i < C; i++) a = fmaf(Wr[t*C + i], Ts[i], a);
        out[g * 6 + t] = a;
    }
}

extern "C" void kernel_launch(void* const* d_in, const int* in_sizes, int n_in,
                              void* d_out, int out_size, void* d_ws, size_t ws_size,
                              hipStream_t stream) {
    const float* x   = (const float*)d_in[0];
    const float* pos = (const float*)d_in[1];
    // d_in[2] = batch (int64) unused: nodes are contiguous M-per-graph
    const float* W1a = (const float*)d_in[3];
    const float* b1a = (const float*)d_in[4];
    const float* W2a = (const float*)d_in[5];
    const float* b2a = (const float*)d_in[6];
    const float* W1b = (const float*)d_in[7];
    const float* b1b = (const float*)d_in[8];
    const float* W2b = (const float*)d_in[9];
    const float* b2b = (const float*)d_in[10];
    const float* W1c = (const float*)d_in[11];
    const float* b1c = (const float*)d_in[12];
    const float* W2c = (const float*)d_in[13];
    const float* b2c = (const float*)d_in[14];
    const float* Wr  = (const float*)d_in[15];
    const float* br  = (const float*)d_in[16];

    float* out = (float*)d_out;

    megafused_kernel<<<NB, 1024, 0, stream>>>(x, pos,
                                              W1a, b1a, W2a, b2a,
                                              W1b, b1b, W2b, b2b,
                                              W1c, b1c, W2c, b2c,
                                              Wr, br, out);
}

// Round 11
// 180.189 us; speedup vs baseline: 1.3381x; 1.1216x over previous
//
#include <hip/hip_runtime.h>
#include <cstddef>

#define NB 256     // graphs
#define M 512      // nodes per graph
#define KNN 6      // neighbors
#define C 32       // channels

// ---------------------------------------------------------------------------
// ONE kernel: block = graph (1024 threads = 512 nodes x 2 channel-halves),
// phases: in-block KNN -> L1 -> L2 -> L3 -> pool -> head. (round-10 base,
// absmax 0.0; 16 waves/CU from a single block.)
// Round-11: (1) med3 value-chain in KNN insert (identical values: med3 of
// {dist, d[k-1], d[k]} == the cndmask insert; index selects keep the exact
// strict-< compares -> same tie rule); (2) m1 half-split via Ts exchange
// (kills the duplicated 32x32 m1, +2 barriers/layer); (3) relu folded into
// aggregation init (relu(max_k T) == max(0, T...), exact).
// ---------------------------------------------------------------------------
__global__ __launch_bounds__(1024, 1) void megafused_kernel(
    const float* __restrict__ x, const float* __restrict__ pos,
    const float* __restrict__ W1a, const float* __restrict__ b1a,
    const float* __restrict__ W2a, const float* __restrict__ b2a,
    const float* __restrict__ W1b, const float* __restrict__ b1b,
    const float* __restrict__ W2b, const float* __restrict__ b2b,
    const float* __restrict__ W1c, const float* __restrict__ b1c,
    const float* __restrict__ W2c, const float* __restrict__ b2c,
    const float* __restrict__ Wr,  const float* __restrict__ br,
    float* __restrict__ out)
{
    __shared__ __align__(16) float Ts[M * C];   // 64 KB, multi-purpose
    const int g  = blockIdx.x;
    const int t  = threadIdx.x;
    const int n  = t & (M - 1);                 // node 0..511
    const int hv = t >> 9;                      // 0/1, wave-uniform
    const int c0 = __builtin_amdgcn_readfirstlane(hv << 4); // SGPR weight base

    // ---- overlay for KNN phase (within the 64 KB of Ts) ----
    float4* sp          = (float4*)Ts;                          // [0, 8K) B
    float*  cd          = Ts + 2048;                            // [8K, 36K) B, stride 7
    unsigned short* ci  = (unsigned short*)(Ts + 2048 + 7168);  // [36K, 50K) B

    // === phase 0: positions + squared norms into LDS ===
    const float* p = pos + (size_t)g * M * 3;
    if (t < M) {
        float xx = p[3*t], yy = p[3*t+1], zz = p[3*t+2];
        sp[t] = make_float4(xx, yy, zz, fmaf(xx, xx, fmaf(yy, yy, zz * zz)));
    }
    __syncthreads();

    const float4 pm = sp[n];

    // === phase 1: KNN scan — row n, cols [hv*256, hv*256+256) ===
    float d0 = INFINITY, d1 = INFINITY, d2 = INFINITY,
          d3 = INFINITY, d4 = INFINITY, d5 = INFINITY;
    int   i0 = -1, i1 = -1, i2 = -1, i3 = -1, i4 = -1, i5 = -1;

    const int col0 = hv << 8;
#pragma unroll 4
    for (int jj = 0; jj < 256; jj++) {
        const int col = col0 + jj;
        const float4 pn = sp[col];                       // wave-uniform broadcast
        float dot  = fmaf(pm.x, pn.x, fmaf(pm.y, pn.y, pm.z * pn.z));
        float dist = fmaf(-2.f, dot, pm.w + pn.w);       // validated rounding chain
        // compares on OLD d values (strict < => lowest index wins on ties)
        bool c5 = dist < d5, c4 = dist < d4, c3 = dist < d3,
             c2 = dist < d2, c1 = dist < d1, cz = dist < d0;
        // index shift (descending: uses old neighbors)
        i5 = c4 ? i4 : (c5 ? col : i5);
        i4 = c3 ? i3 : (c4 ? col : i4);
        i3 = c2 ? i2 : (c3 ? col : i3);
        i2 = c1 ? i1 : (c2 ? col : i2);
        i1 = cz ? i0 : (c1 ? col : i1);
        i0 = cz ? col : i0;
        // value chain via med3 (descending: uses old values)
        d5 = __builtin_amdgcn_fmed3f(dist, d4, d5);
        d4 = __builtin_amdgcn_fmed3f(dist, d3, d4);
        d3 = __builtin_amdgcn_fmed3f(dist, d2, d3);
        d2 = __builtin_amdgcn_fmed3f(dist, d1, d2);
        d1 = __builtin_amdgcn_fmed3f(dist, d0, d1);
        d0 = fminf(dist, d0);
    }
    {
        float* cdp = cd + t * 7;
        cdp[0]=d0; cdp[1]=d1; cdp[2]=d2; cdp[3]=d3; cdp[4]=d4; cdp[5]=d5;
        unsigned short* cip = ci + t * 7;
        cip[0]=(unsigned short)i0; cip[1]=(unsigned short)i1;
        cip[2]=(unsigned short)i2; cip[3]=(unsigned short)i3;
        cip[4]=(unsigned short)i4; cip[5]=(unsigned short)i5;
    }
    __syncthreads();

    // === phase 2: merge the two 6-lists of node n (ascending halves ->
    // strict-< insert is tie-stable toward lower index); both half-threads
    // compute the same j[] redundantly, it stays in registers ===
    int j[KNN];
    {
        float md[KNN]; int mi[KNN];
#pragma unroll
        for (int k = 0; k < KNN; k++) { md[k] = cd[n*7 + k]; mi[k] = ci[n*7 + k]; }
        const int L1 = (n + M) * 7;
#pragma unroll
        for (int k = 0; k < KNN; k++) {
            float dist = cd[L1 + k];
            int   nn   = ci[L1 + k];
            bool c5 = dist < md[5], c4 = dist < md[4], c3 = dist < md[3],
                 c2 = dist < md[2], c1 = dist < md[1], cz = dist < md[0];
            mi[5] = c4 ? mi[4] : (c5 ? nn : mi[5]);
            mi[4] = c3 ? mi[3] : (c4 ? nn : mi[4]);
            mi[3] = c2 ? mi[2] : (c3 ? nn : mi[3]);
            mi[2] = c1 ? mi[1] : (c2 ? nn : mi[2]);
            mi[1] = cz ? mi[0] : (c1 ? nn : mi[1]);
            mi[0] = cz ? nn : mi[0];
            md[5] = __builtin_amdgcn_fmed3f(dist, md[4], md[5]);
            md[4] = __builtin_amdgcn_fmed3f(dist, md[3], md[4]);
            md[3] = __builtin_amdgcn_fmed3f(dist, md[2], md[3]);
            md[2] = __builtin_amdgcn_fmed3f(dist, md[1], md[2]);
            md[1] = __builtin_amdgcn_fmed3f(dist, md[0], md[1]);
            md[0] = fminf(dist, md[0]);
        }
#pragma unroll
        for (int k = 0; k < KNN; k++) j[k] = mi[k];
    }
    __syncthreads();   // KNN scratch dead; Ts becomes the T-staging buffer

    const int np = n & 7;

    // === layer 1: T1 = MLP_a([x,pos]) — no gather ===
    {
        const float h0 = x[(size_t)g * M + n];
        const float h1 = pm.x, h2 = pm.y, h3 = pm.z;
        float m1[C];
#pragma unroll
        for (int o = 0; o < C; o++) {
            float a = b1a[o];
            a = fmaf(W1a[o*4+0], h0, a);
            a = fmaf(W1a[o*4+1], h1, a);
            a = fmaf(W1a[o*4+2], h2, a);
            a = fmaf(W1a[o*4+3], h3, a);
            m1[o] = fmaxf(a, 0.f);
        }
#pragma unroll
        for (int q2 = 0; q2 < 4; q2++) {
            float4 v; float* vp = &v.x;
#pragma unroll
            for (int u = 0; u < 4; u++) {
                const int o = c0 + q2*4 + u;
                float a = b2a[o];
#pragma unroll
                for (int i = 0; i < C; i++) a = fmaf(W2a[o*C + i], m1[i], a);
                vp[u] = a;
            }
            const int q = 4*hv + q2;
            *(float4*)&Ts[n*C + ((q ^ np) << 2)] = v;
        }
    }
    __syncthreads();

    // === layers 2,3 ===
#pragma unroll 1
    for (int layer = 0; layer < 2; layer++) {
        const float* W1 = layer ? W1c : W1b;
        const float* b1 = layer ? b1c : b1b;
        const float* W2 = layer ? W2c : W2b;
        const float* b2 = layer ? b2c : b2b;

        // A: aggregate neighbors' half-rows; 0-init folds the relu (exact)
        float hm[16];
#pragma unroll
        for (int u = 0; u < 16; u++) hm[u] = 0.f;
#pragma unroll
        for (int k = 0; k < KNN; k++) {
            const int jl = j[k], jp = jl & 7;
#pragma unroll
            for (int q2 = 0; q2 < 4; q2++) {
                const int q = 4*hv + q2;
                const float4 v = *(const float4*)&Ts[jl*C + ((q ^ jp) << 2)];
                hm[4*q2+0] = fmaxf(hm[4*q2+0], v.x);
                hm[4*q2+1] = fmaxf(hm[4*q2+1], v.y);
                hm[4*q2+2] = fmaxf(hm[4*q2+2], v.z);
                hm[4*q2+3] = fmaxf(hm[4*q2+3], v.w);
            }
        }
        __syncthreads();              // all T reads done
        // B: write h half-row (overwrites T)
#pragma unroll
        for (int q2 = 0; q2 < 4; q2++) {
            const int q = 4*hv + q2;
            *(float4*)&Ts[n*C + ((q ^ np) << 2)] =
                make_float4(hm[4*q2], hm[4*q2+1], hm[4*q2+2], hm[4*q2+3]);
        }
        __syncthreads();              // h visible
        // C: read full h row of own node
        float hf[C];
#pragma unroll
        for (int q = 0; q < 8; q++) {
            const float4 v = *(const float4*)&Ts[n*C + ((q ^ np) << 2)];
            hf[4*q+0] = v.x; hf[4*q+1] = v.y; hf[4*q+2] = v.z; hf[4*q+3] = v.w;
        }
        __syncthreads();              // h reads done (m1 write below aliases)
        // D: m1 HALF (16 outs x 32 ins) — the duplicated full-m1 is gone
        float m1h[16];
#pragma unroll
        for (int o2 = 0; o2 < 16; o2++) {
            const int o = c0 + o2;
            float a = b1[o];
#pragma unroll
            for (int i = 0; i < C; i++) a = fmaf(W1[o*C + i], hf[i], a);
            m1h[o2] = fmaxf(a, 0.f);
        }
#pragma unroll
        for (int q2 = 0; q2 < 4; q2++) {
            const int q = 4*hv + q2;
            *(float4*)&Ts[n*C + ((q ^ np) << 2)] =
                make_float4(m1h[4*q2], m1h[4*q2+1], m1h[4*q2+2], m1h[4*q2+3]);
        }
        __syncthreads();              // m1 visible
        // E: read full m1 row
        float m1[C];
#pragma unroll
        for (int q = 0; q < 8; q++) {
            const float4 v = *(const float4*)&Ts[n*C + ((q ^ np) << 2)];
            m1[4*q+0] = v.x; m1[4*q+1] = v.y; m1[4*q+2] = v.z; m1[4*q+3] = v.w;
        }
        __syncthreads();              // m1 reads done (T write aliases)
        // F: T half-row
#pragma unroll
        for (int q2 = 0; q2 < 4; q2++) {
            float4 v; float* vp = &v.x;
#pragma unroll
            for (int u = 0; u < 4; u++) {
                const int o = c0 + q2*4 + u;
                float a = b2[o];
#pragma unroll
                for (int i = 0; i < C; i++) a = fmaf(W2[o*C + i], m1[i], a);
                vp[u] = a;
            }
            const int q = 4*hv + q2;
            *(float4*)&Ts[n*C + ((q ^ np) << 2)] = v;
        }
        __syncthreads();              // T visible
    }

    // === final aggregation (h3) for pooling; 0-init folds the relu ===
    {
        float hm[16];
#pragma unroll
        for (int u = 0; u < 16; u++) hm[u] = 0.f;
#pragma unroll
        for (int k = 0; k < KNN; k++) {
            const int jl = j[k], jp = jl & 7;
#pragma unroll
            for (int q2 = 0; q2 < 4; q2++) {
                const int q = 4*hv + q2;
                const float4 v = *(const float4*)&Ts[jl*C + ((q ^ jp) << 2)];
                hm[4*q2+0] = fmaxf(hm[4*q2+0], v.x);
                hm[4*q2+1] = fmaxf(hm[4*q2+1], v.y);
                hm[4*q2+2] = fmaxf(hm[4*q2+2], v.z);
                hm[4*q2+3] = fmaxf(hm[4*q2+3], v.w);
            }
        }
        __syncthreads();              // all T3 reads done
#pragma unroll
        for (int q2 = 0; q2 < 4; q2++) {
            const int q = 4*hv + q2;
            *(float4*)&Ts[n*C + ((q ^ np) << 2)] =
                make_float4(hm[4*q2], hm[4*q2+1], hm[4*q2+2], hm[4*q2+3]);
        }
        __syncthreads();
    }

    // === global max pool: tree reduce rows 512 -> 32 (round-6 validated) ===
    const int tp = t & 7;
    for (int s = 256; s >= 32; s >>= 1) {
        if (t < s) {
#pragma unroll
            for (int q = 0; q < 8; q++) {
                const int ph = (q ^ tp) << 2;
                float4 a = *(const float4*)&Ts[t*C + ph];
                float4 b = *(const float4*)&Ts[(t + s)*C + ph];
                a.x = fmaxf(a.x, b.x); a.y = fmaxf(a.y, b.y);
                a.z = fmaxf(a.z, b.z); a.w = fmaxf(a.w, b.w);
                *(float4*)&Ts[t*C + ph] = a;
            }
        }
        __syncthreads();
    }

    if (t < C) {   // wave 0: reduce final 32 rows (reads precede write in-wave)
        float m = -INFINITY;
#pragma unroll
        for (int r = 0; r < 32; r++)
            m = fmaxf(m, Ts[r*C + ((((t >> 2) ^ (r & 7)) << 2) | (t & 3))]);
        Ts[t] = m;
    }
    __syncthreads();

    if (t < 6) {
        float a = br[t];
#pragma unroll
        for (int i = 0; i < C; i++) a = fmaf(Wr[t*C + i], Ts[i], a);
        out[g * 6 + t] = a;
    }
}

extern "C" void kernel_launch(void* const* d_in, const int* in_sizes, int n_in,
                              void* d_out, int out_size, void* d_ws, size_t ws_size,
                              hipStream_t stream) {
    const float* x   = (const float*)d_in[0];
    const float* pos = (const float*)d_in[1];
    // d_in[2] = batch (int64) unused: nodes are contiguous M-per-graph
    const float* W1a = (const float*)d_in[3];
    const float* b1a = (const float*)d_in[4];
    const float* W2a = (const float*)d_in[5];
    const float* b2a = (const float*)d_in[6];
    const float* W1b = (const float*)d_in[7];
    const float* b1b = (const float*)d_in[8];
    const float* W2b = (const float*)d_in[9];
    const float* b2b = (const float*)d_in[10];
    const float* W1c = (const float*)d_in[11];
    const float* b1c = (const float*)d_in[12];
    const float* W2c = (const float*)d_in[13];
    const float* b2c = (const float*)d_in[14];
    const float* Wr  = (const float*)d_in[15];
    const float* br  = (const float*)d_in[16];

    float* out = (float*)d_out;

    megafused_kernel<<<NB, 1024, 0, stream>>>(x, pos,
                                              W1a, b1a, W2a, b2a,
                                              W1b, b1b, W2b, b2b,
                                              W1c, b1c, W2c, b2c,
                                              Wr, br, out);
}